// Round 5
// baseline (321.993 us; speedup 1.0000x reference)
//
#include <hip/hip_runtime.h>
#include <cstddef>

#define C 128

typedef short bf16x8 __attribute__((ext_vector_type(8)));
typedef float f32x4 __attribute__((ext_vector_type(4)));

__device__ __forceinline__ unsigned short f2bf_rne(float f) {
  unsigned u = __float_as_uint(f);
  unsigned r = u + 0x7fffu + ((u >> 16) & 1u);
  return (unsigned short)(r >> 16);
}

// ---- W prep: W[j][k][c] fp32 -> Wt_hi/Wt_lo[j][c][k] bf16 (transposed) ----
__global__ __launch_bounds__(256) void prep_w(
    const float* __restrict__ W, unsigned short* __restrict__ wt_hi,
    unsigned short* __restrict__ wt_lo) {
  const int idx = blockIdx.x * 256 + threadIdx.x;  // 0..49151
  const int j = idx >> 14;
  const int k = (idx >> 7) & 127;
  const int c = idx & 127;
  const float v = W[idx];
  const unsigned short h = f2bf_rne(v);
  const float hf = __uint_as_float(((unsigned)h) << 16);
  const unsigned short l = f2bf_rne(v - hf);
  const int dst = (j << 14) | (c << 7) | k;
  wt_hi[dst] = h;
  wt_lo[dst] = l;
}

// ---- fused 3x linear via MFMA split-bf16 ------------------------------
// block = 256 thr (4 waves); wave = 16 rows x 128 cols; block = 64 rows.
// j-loop internal: x staged+converted once, reused for all 3 weights.
__global__ __launch_bounds__(256, 4) void gemm3_mfma(
    const float* __restrict__ x, const unsigned short* __restrict__ wt_hi,
    const unsigned short* __restrict__ wt_lo, const float* __restrict__ bias,
    float* __restrict__ out, float* __restrict__ h1, float* __restrict__ h2,
    int N) {
  __shared__ float xs[64][132];  // +4 pad: conflict-free b128 reads
  const int row0 = blockIdx.x * 64;
  const int tid = threadIdx.x;

  // stage 64x128 x tile (coalesced float4)
#pragma unroll
  for (int it = 0; it < 8; ++it) {
    const int f = it * 256 + tid;
    const int r = f >> 5;
    const int cq = (f & 31) << 2;
    const int gr = row0 + r;
    float4 v = make_float4(0.f, 0.f, 0.f, 0.f);
    if (gr < N) v = *reinterpret_cast<const float4*>(x + (size_t)gr * C + cq);
    *reinterpret_cast<float4*>(&xs[r][cq]) = v;
  }
  __syncthreads();

  const int lane = tid & 63;
  const int wid = tid >> 6;
  const int l15 = lane & 15;
  const int g = lane >> 4;          // k-group 0..3
  const int rloc = wid * 16 + l15;  // A-frag row (local)

  // convert A fragments once: A[m=l15][k=8g+i], 4 k-chunks, hi+lo
  bf16x8 ah[4], al[4];
#pragma unroll
  for (int kc = 0; kc < 4; ++kc) {
    const float* sp = &xs[rloc][kc * 32 + g * 8];
    const float4 pa = *reinterpret_cast<const float4*>(sp);
    const float4 pb = *reinterpret_cast<const float4*>(sp + 4);
    const float vv[8] = {pa.x, pa.y, pa.z, pa.w, pb.x, pb.y, pb.z, pb.w};
    bf16x8 h, l;
#pragma unroll
    for (int i = 0; i < 8; ++i) {
      const unsigned u = __float_as_uint(vv[i]);
      const unsigned hb = (u + 0x7fffu + ((u >> 16) & 1u)) >> 16;
      h[i] = (short)hb;
      const float rem = vv[i] - __uint_as_float(hb << 16);
      const unsigned u2 = __float_as_uint(rem);
      l[i] = (short)((u2 + 0x7fffu + ((u2 >> 16) & 1u)) >> 16);
    }
    ah[kc] = h;
    al[kc] = l;
  }

#pragma unroll
  for (int j = 0; j < 3; ++j) {
    const unsigned short* __restrict__ Bh = wt_hi + (size_t)j * 16384;
    const unsigned short* __restrict__ Bl = wt_lo + (size_t)j * 16384;
    f32x4 acc[8];
#pragma unroll
    for (int ct = 0; ct < 8; ++ct) acc[ct] = (f32x4){0.f, 0.f, 0.f, 0.f};

#pragma unroll
    for (int kc = 0; kc < 4; ++kc) {
      const int ko = kc * 32 + g * 8;
#pragma unroll
      for (int ct = 0; ct < 8; ++ct) {
        const int boff = (ct * 16 + l15) * 128 + ko;  // Wt[col][k]
        const bf16x8 bh = *reinterpret_cast<const bf16x8*>(Bh + boff);
        const bf16x8 bl = *reinterpret_cast<const bf16x8*>(Bl + boff);
        acc[ct] = __builtin_amdgcn_mfma_f32_16x16x32_bf16(ah[kc], bh, acc[ct], 0, 0, 0);
        acc[ct] = __builtin_amdgcn_mfma_f32_16x16x32_bf16(ah[kc], bl, acc[ct], 0, 0, 0);
        acc[ct] = __builtin_amdgcn_mfma_f32_16x16x32_bf16(al[kc], bh, acc[ct], 0, 0, 0);
      }
    }

    // epilogue: D col=lane&15, row=4*(lane>>4)+q  [m89]
    float* const bp = (j == 0) ? out : ((j == 1) ? h1 : h2);
    const int stride = (j == 0) ? 384 : C;
#pragma unroll
    for (int ct = 0; ct < 8; ++ct) {
      const int col = ct * 16 + l15;
      const float bv = bias[j * C + col];
#pragma unroll
      for (int q = 0; q < 4; ++q) {
        const int gr = row0 + wid * 16 + g * 4 + q;
        if (gr < N) bp[(size_t)gr * stride + col] = acc[ct][q] + bv;
      }
    }
  }
}

// ---- CSR build --------------------------------------------------------
__global__ __launch_bounds__(256) void hist_rows(
    const int* __restrict__ row, int* __restrict__ cnt, int E) {
  int i = blockIdx.x * 256 + threadIdx.x;
  int stride = gridDim.x * 256;
  for (; i < E; i += stride) atomicAdd(&cnt[row[i]], 1);
}

__global__ __launch_bounds__(1024) void scan_local(
    const int* __restrict__ cnt, int* __restrict__ part,
    int* __restrict__ bsum, int N) {
  __shared__ int wsum[16];
  const int tid = threadIdx.x;
  const int i = blockIdx.x * 1024 + tid;
  const int v = (i < N) ? cnt[i] : 0;
  const int lane = tid & 63, w = tid >> 6;
  int s = v;
#pragma unroll
  for (int off = 1; off < 64; off <<= 1) {
    int t = __shfl_up(s, off, 64);
    if (lane >= off) s += t;
  }
  if (lane == 63) wsum[w] = s;
  __syncthreads();
  if (tid < 16) {
    int ws = wsum[tid];
#pragma unroll
    for (int off = 1; off < 16; off <<= 1) {
      int t = __shfl_up(ws, off, 16);
      if (tid >= off) ws += t;
    }
    wsum[tid] = ws;
  }
  __syncthreads();
  const int woff = w ? wsum[w - 1] : 0;
  if (i < N) part[i] = woff + s - v;
  if (tid == 0) bsum[blockIdx.x] = wsum[15];
}

__global__ __launch_bounds__(64) void scan_carry(
    const int* __restrict__ bsum, int* __restrict__ carry,
    int* __restrict__ row_ptr, int nb, int N) {
  const int tid = threadIdx.x;
  const int v = (tid < nb) ? bsum[tid] : 0;
  int s = v;
#pragma unroll
  for (int off = 1; off < 64; off <<= 1) {
    int t = __shfl_up(s, off, 64);
    if (tid >= off) s += t;
  }
  if (tid < nb) carry[tid] = s - v;
  if (tid == 63) row_ptr[N] = s;
}

__global__ __launch_bounds__(1024) void scan_apply(
    int* __restrict__ part, const int* __restrict__ carry,
    int* __restrict__ cursor, int N) {
  const int i = blockIdx.x * 1024 + threadIdx.x;
  if (i < N) {
    const int v = part[i] + carry[blockIdx.x];
    part[i] = v;
    cursor[i] = v;
  }
}

__global__ __launch_bounds__(256) void scatter_edges(
    const int* __restrict__ row, const int* __restrict__ col,
    const float* __restrict__ val, int* __restrict__ cursor,
    int2* __restrict__ ep, int E) {
  int i = blockIdx.x * 256 + threadIdx.x;
  int stride = gridDim.x * 256;
  for (; i < E; i += stride) {
    int r = row[i];
    int pos = atomicAdd(&cursor[r], 1);
    ep[pos] = make_int2(col[i], __float_as_int(val[i]));
  }
}

// ---- SpMM single: one row per wave, float2 per lane -------------------
__global__ __launch_bounds__(256) void spmm_csr(
    const float* __restrict__ h, const int* __restrict__ rp,
    const int2* __restrict__ ep, float* __restrict__ outp,
    int N, int ostride) {
  const int r = blockIdx.x * 4 + (threadIdx.x >> 6);
  if (r >= N) return;
  const int c2 = (threadIdx.x & 63) << 1;
  const int s = rp[r];
  const int e = rp[r + 1];
  float2 a0 = make_float2(0.f, 0.f), a1 = a0, a2 = a0, a3 = a0;
  int i = s;
  for (; i + 3 < e; i += 4) {
    const int2 e0 = ep[i], e1 = ep[i + 1], e2 = ep[i + 2], e3 = ep[i + 3];
    const float2 g0 = *reinterpret_cast<const float2*>(h + (size_t)e0.x * C + c2);
    const float2 g1 = *reinterpret_cast<const float2*>(h + (size_t)e1.x * C + c2);
    const float2 g2 = *reinterpret_cast<const float2*>(h + (size_t)e2.x * C + c2);
    const float2 g3 = *reinterpret_cast<const float2*>(h + (size_t)e3.x * C + c2);
    const float v0 = __int_as_float(e0.y), v1 = __int_as_float(e1.y);
    const float v2 = __int_as_float(e2.y), v3 = __int_as_float(e3.y);
    a0.x += v0 * g0.x; a0.y += v0 * g0.y;
    a1.x += v1 * g1.x; a1.y += v1 * g1.y;
    a2.x += v2 * g2.x; a2.y += v2 * g2.y;
    a3.x += v3 * g3.x; a3.y += v3 * g3.y;
  }
  for (; i < e; ++i) {
    const int2 e0 = ep[i];
    const float v0 = __int_as_float(e0.y);
    const float2 g0 = *reinterpret_cast<const float2*>(h + (size_t)e0.x * C + c2);
    a0.x += v0 * g0.x; a0.y += v0 * g0.y;
  }
  float2 res;
  res.x = (a0.x + a1.x) + (a2.x + a3.x);
  res.y = (a0.y + a1.y) + (a2.y + a3.y);
  *reinterpret_cast<float2*>(outp + (size_t)r * ostride + c2) = res;
}

// ---- SpMM merged: pass1 (h1 -> out[:,128:256]) and pass2a (h2 -> t) ----
// one edge loop, one ep read per edge, both gathers share loop overhead.
__global__ __launch_bounds__(256) void spmm12(
    const float* __restrict__ h1, const float* __restrict__ h2,
    const int* __restrict__ rp, const int2* __restrict__ ep,
    float* __restrict__ out, float* __restrict__ t, int N) {
  const int r = blockIdx.x * 4 + (threadIdx.x >> 6);
  if (r >= N) return;
  const int c2 = (threadIdx.x & 63) << 1;
  const int s = rp[r];
  const int e = rp[r + 1];
  float2 p0 = make_float2(0.f, 0.f), p1 = p0, q0 = p0, q1 = p0;
  int i = s;
  for (; i + 1 < e; i += 2) {
    const int2 e0 = ep[i], e1 = ep[i + 1];
    const float v0 = __int_as_float(e0.y), v1 = __int_as_float(e1.y);
    const float2 a0 = *reinterpret_cast<const float2*>(h1 + (size_t)e0.x * C + c2);
    const float2 b0 = *reinterpret_cast<const float2*>(h2 + (size_t)e0.x * C + c2);
    const float2 a1 = *reinterpret_cast<const float2*>(h1 + (size_t)e1.x * C + c2);
    const float2 b1 = *reinterpret_cast<const float2*>(h2 + (size_t)e1.x * C + c2);
    p0.x += v0 * a0.x; p0.y += v0 * a0.y;
    q0.x += v0 * b0.x; q0.y += v0 * b0.y;
    p1.x += v1 * a1.x; p1.y += v1 * a1.y;
    q1.x += v1 * b1.x; q1.y += v1 * b1.y;
  }
  if (i < e) {
    const int2 e0 = ep[i];
    const float v0 = __int_as_float(e0.y);
    const float2 a0 = *reinterpret_cast<const float2*>(h1 + (size_t)e0.x * C + c2);
    const float2 b0 = *reinterpret_cast<const float2*>(h2 + (size_t)e0.x * C + c2);
    p0.x += v0 * a0.x; p0.y += v0 * a0.y;
    q0.x += v0 * b0.x; q0.y += v0 * b0.y;
  }
  float2 rp1, rq;
  rp1.x = p0.x + p1.x; rp1.y = p0.y + p1.y;
  rq.x = q0.x + q1.x; rq.y = q0.y + q1.y;
  *reinterpret_cast<float2*>(out + (size_t)r * 384 + C + c2) = rp1;
  *reinterpret_cast<float2*>(t + (size_t)r * C + c2) = rq;
}

extern "C" void kernel_launch(void* const* d_in, const int* in_sizes, int n_in,
                              void* d_out, int out_size, void* d_ws, size_t ws_size,
                              hipStream_t stream) {
  const float* x  = (const float*)d_in[0];
  const float* W  = (const float*)d_in[1];
  const float* b  = (const float*)d_in[2];
  const float* ev = (const float*)d_in[3];
  const int*   er = (const int*)d_in[4];
  const int*   ec = (const int*)d_in[5];
  const int N = in_sizes[0] / C;
  const int E = in_sizes[3];
  float* out = (float*)d_out;

  const size_t NB = (size_t)N * C;
  const size_t WT = 3 * 128 * 128;  // ushorts per wt buffer

  // does ws fit the merged-spmm layout (3 fp32 N x C buffers)?
  const size_t need_merged = 3 * NB * 4 + ((size_t)2 * N + 1 + 128) * 4 +
                             2 * WT * 2 + (size_t)E * 8;
  const bool merged = ws_size >= need_merged;

  char* ws = (char*)d_ws;
  float* h1 = (float*)ws;  ws += NB * sizeof(float);
  float* h2 = (float*)ws;  ws += NB * sizeof(float);
  float* t;
  if (merged) { t = (float*)ws; ws += NB * sizeof(float); }
  else        { t = h1; }  // fallback: h1 dead after pass-1 spmm
  int* row_ptr = (int*)ws;  ws += (size_t)(N + 1) * sizeof(int);
  int* cursor  = (int*)ws;  ws += (size_t)N * sizeof(int);
  int* bsum    = (int*)ws;  ws += 64 * sizeof(int);
  int* carry   = (int*)ws;  ws += 64 * sizeof(int);
  unsigned short* wt_hi = (unsigned short*)ws;  ws += WT * sizeof(unsigned short);
  unsigned short* wt_lo = (unsigned short*)ws;  ws += WT * sizeof(unsigned short);
  int2* ep = (int2*)ws;

  const int nb = (N + 1023) / 1024;

  // W split+transpose (tiny)
  prep_w<<<(int)(WT / 256), 256, 0, stream>>>(W, wt_hi, wt_lo);

  // CSR build (cursor doubles as count buffer)
  hipMemsetAsync(cursor, 0, (size_t)N * sizeof(int), stream);
  const int eb0 = (E + 255) / 256;
  const int eblocks = eb0 < 2048 ? eb0 : 2048;
  hist_rows<<<eblocks, 256, 0, stream>>>(er, cursor, E);
  scan_local<<<nb, 1024, 0, stream>>>(cursor, row_ptr, bsum, N);
  scan_carry<<<1, 64, 0, stream>>>(bsum, carry, row_ptr, nb, N);
  scan_apply<<<nb, 1024, 0, stream>>>(row_ptr, carry, cursor, N);
  scatter_edges<<<eblocks, 256, 0, stream>>>(er, ec, ev, cursor, ep, E);

  // fused linears (MFMA split-bf16)
  gemm3_mfma<<<(N + 63) / 64, 256, 0, stream>>>(x, wt_hi, wt_lo, b, out, h1, h2, N);

  // SpMM passes
  const int sblocks = (N + 3) / 4;
  if (merged) {
    spmm12<<<sblocks, 256, 0, stream>>>(h1, h2, row_ptr, ep, out, t, N);
  } else {
    spmm_csr<<<sblocks, 256, 0, stream>>>(h1, row_ptr, ep, out + C, N, 3 * C);
    spmm_csr<<<sblocks, 256, 0, stream>>>(h2, row_ptr, ep, t, N, C);
  }
  spmm_csr<<<sblocks, 256, 0, stream>>>(t, row_ptr, ep, out + 2 * C, N, 3 * C);
}

// Round 6
// 257.907 us; speedup vs baseline: 1.2485x; 1.2485x over previous
//
#include <hip/hip_runtime.h>
#include <hip/hip_fp16.h>
#include <cstddef>
#include <cstdint>

#define C 128

typedef short bf16x8 __attribute__((ext_vector_type(8)));
typedef float f32x4 __attribute__((ext_vector_type(4)));

__device__ __forceinline__ unsigned f2bf_hi(float f) {
  unsigned u = __float_as_uint(f);
  return (u + 0x7fffu + ((u >> 16) & 1u)) >> 16;
}

// ---- W prep: W[j][k][c] fp32 -> swizzled bf16 hi/lo planes [j][c][k^] ----
__global__ __launch_bounds__(256) void prep_w(
    const float* __restrict__ W, unsigned short* __restrict__ wh,
    unsigned short* __restrict__ wl) {
  const int idx = blockIdx.x * 256 + threadIdx.x;  // 0..49151
  const int j = idx >> 14, k = (idx >> 7) & 127, c = idx & 127;
  const float v = W[idx];
  const unsigned hb = f2bf_hi(v);
  const float hf = __uint_as_float(hb << 16);
  const unsigned lb = f2bf_hi(v - hf);
  const int dst = (j << 14) + c * 128 + (k ^ ((c & 7) << 3));
  wh[dst] = (unsigned short)hb;
  wl[dst] = (unsigned short)lb;
}

// ---- x prep: fp32 [N][128] -> bf16 hi/lo [NP][128] (zero-padded rows) ----
__global__ __launch_bounds__(256) void prep_x(
    const float* __restrict__ x, unsigned short* __restrict__ xh,
    unsigned short* __restrict__ xl, int N, int NP) {
  const int idx = blockIdx.x * 256 + threadIdx.x;
  if (idx >= NP * C) return;
  const float v = (idx < N * C) ? x[idx] : 0.0f;
  const unsigned hb = f2bf_hi(v);
  const float hf = __uint_as_float(hb << 16);
  const unsigned lb = f2bf_hi(v - hf);
  xh[idx] = (unsigned short)hb;
  xl[idx] = (unsigned short)lb;
}

// ---- fused 3x linear via MFMA split-bf16, LDS-staged W panels ----------
// block 256 thr (4 waves) = 64 rows; wave = 16 rows x 128 cols.
__global__ __launch_bounds__(256) void gemm3_mfma(
    const unsigned short* __restrict__ xh, const unsigned short* __restrict__ xl,
    const unsigned short* __restrict__ wh, const unsigned short* __restrict__ wl,
    const float* __restrict__ bias, float* __restrict__ out,
    __half* __restrict__ h1, __half* __restrict__ h2, int N) {
  __shared__ unsigned short wlds[2][16384];  // 2 x 32KB panels
  const int row0 = blockIdx.x * 64;
  const int tid = threadIdx.x;
  const int lane = tid & 63, wid = tid >> 6;
  const int l15 = lane & 15, g = lane >> 4;

  // A fragments: direct global loads of pre-split bf16 (coalesced 16B)
  const size_t arow = (size_t)(row0 + wid * 16 + l15) * C;
  bf16x8 ah[4], al[4];
#pragma unroll
  for (int kc = 0; kc < 4; ++kc) {
    ah[kc] = *reinterpret_cast<const bf16x8*>(xh + arow + kc * 32 + g * 8);
    al[kc] = *reinterpret_cast<const bf16x8*>(xl + arow + kc * 32 + g * 8);
  }

  const unsigned short* psrc[6] = {wh,         wl,         wh + 16384,
                                   wl + 16384, wh + 32768, wl + 32768};

  int4 sreg[8];
#define LOAD_SREG(src)                                                        \
  {                                                                           \
    _Pragma("unroll") for (int it = 0; it < 8; ++it) sreg[it] =               \
        *reinterpret_cast<const int4*>((src) + (size_t)(it * 256 + tid) * 8); \
  }
#define WRITE_PANEL(b)                                                        \
  {                                                                           \
    _Pragma("unroll") for (int it = 0; it < 8; ++it)                          \
        *reinterpret_cast<int4*>(&wlds[(b)][(it * 256 + tid) * 8]) = sreg[it];\
  }

  f32x4 acc[8];
#pragma unroll
  for (int ct = 0; ct < 8; ++ct) acc[ct] = (f32x4){0.f, 0.f, 0.f, 0.f};

  LOAD_SREG(psrc[0]);
  WRITE_PANEL(0);
  LOAD_SREG(psrc[1]);

  const int swz = (l15 & 7) << 3;
#pragma unroll
  for (int p = 0; p < 6; ++p) {
    __syncthreads();  // panel p visible in buf[p&1]
    const bool hi_half = !(p & 1);
#pragma unroll
    for (int kc = 0; kc < 4; ++kc) {
      const int kbase = (kc * 32 + g * 8) ^ swz;
#pragma unroll
      for (int ct = 0; ct < 8; ++ct) {
        const bf16x8 bf = *reinterpret_cast<const bf16x8*>(
            &wlds[p & 1][(ct * 16 + l15) * 128 + kbase]);
        acc[ct] = __builtin_amdgcn_mfma_f32_16x16x32_bf16(ah[kc], bf, acc[ct], 0, 0, 0);
        if (hi_half)
          acc[ct] = __builtin_amdgcn_mfma_f32_16x16x32_bf16(al[kc], bf, acc[ct], 0, 0, 0);
      }
    }
    __syncthreads();  // all waves done reading buf[p&1]
    if (p < 5) {
      WRITE_PANEL((p + 1) & 1);          // waits on sreg loads (covered by compute)
      if (p < 4) LOAD_SREG(psrc[p + 2]); // in flight under next compute + epilogue
    }
    if (p & 1) {
      const int j = p >> 1;
      if (j == 0) {
#pragma unroll
        for (int ct = 0; ct < 8; ++ct) {
          const int col = ct * 16 + l15;
          const float bv = bias[col];
#pragma unroll
          for (int q = 0; q < 4; ++q) {
            const int gr = row0 + wid * 16 + g * 4 + q;
            if (gr < N) out[(size_t)gr * 384 + col] = acc[ct][q] + bv;
          }
        }
      } else {
        __half* const hp = (j == 1) ? h1 : h2;
#pragma unroll
        for (int ct = 0; ct < 8; ++ct) {
          const int col = ct * 16 + l15;
          const float bv = bias[j * C + col];
#pragma unroll
          for (int q = 0; q < 4; ++q) {
            const int gr = row0 + wid * 16 + g * 4 + q;
            if (gr < N) hp[(size_t)gr * C + col] = __float2half(acc[ct][q] + bv);
          }
        }
      }
#pragma unroll
      for (int ct = 0; ct < 8; ++ct) acc[ct] = (f32x4){0.f, 0.f, 0.f, 0.f};
    }
  }
#undef LOAD_SREG
#undef WRITE_PANEL
}

// ---- CSR build --------------------------------------------------------
__global__ __launch_bounds__(256) void hist_rows(
    const int* __restrict__ row, int* __restrict__ cnt, int E) {
  int i = blockIdx.x * 256 + threadIdx.x;
  int stride = gridDim.x * 256;
  for (; i < E; i += stride) atomicAdd(&cnt[row[i]], 1);
}

__global__ __launch_bounds__(1024) void scan_local(
    const int* __restrict__ cnt, int* __restrict__ part,
    int* __restrict__ bsum, int N) {
  __shared__ int wsum[16];
  const int tid = threadIdx.x;
  const int i = blockIdx.x * 1024 + tid;
  const int v = (i < N) ? cnt[i] : 0;
  const int lane = tid & 63, w = tid >> 6;
  int s = v;
#pragma unroll
  for (int off = 1; off < 64; off <<= 1) {
    int t = __shfl_up(s, off, 64);
    if (lane >= off) s += t;
  }
  if (lane == 63) wsum[w] = s;
  __syncthreads();
  if (tid < 16) {
    int ws = wsum[tid];
#pragma unroll
    for (int off = 1; off < 16; off <<= 1) {
      int t = __shfl_up(ws, off, 16);
      if (tid >= off) ws += t;
    }
    wsum[tid] = ws;
  }
  __syncthreads();
  const int woff = w ? wsum[w - 1] : 0;
  if (i < N) part[i] = woff + s - v;
  if (tid == 0) bsum[blockIdx.x] = wsum[15];
}

__global__ __launch_bounds__(64) void scan_carry(
    const int* __restrict__ bsum, int* __restrict__ carry,
    int* __restrict__ row_ptr, int nb, int N) {
  const int tid = threadIdx.x;
  const int v = (tid < nb) ? bsum[tid] : 0;
  int s = v;
#pragma unroll
  for (int off = 1; off < 64; off <<= 1) {
    int t = __shfl_up(s, off, 64);
    if (tid >= off) s += t;
  }
  if (tid < nb) carry[tid] = s - v;
  if (tid == 63) row_ptr[N] = s;
}

__global__ __launch_bounds__(1024) void scan_apply(
    int* __restrict__ part, const int* __restrict__ carry,
    int* __restrict__ cursor, int N) {
  const int i = blockIdx.x * 1024 + threadIdx.x;
  if (i < N) {
    const int v = part[i] + carry[blockIdx.x];
    part[i] = v;
    cursor[i] = v;
  }
}

__global__ __launch_bounds__(256) void scatter_edges(
    const int* __restrict__ row, const int* __restrict__ col,
    const float* __restrict__ val, int* __restrict__ cursor,
    int2* __restrict__ ep, int E) {
  int i = blockIdx.x * 256 + threadIdx.x;
  int stride = gridDim.x * 256;
  for (; i < E; i += stride) {
    int r = row[i];
    int pos = atomicAdd(&cursor[r], 1);
    ep[pos] = make_int2(col[i], __float_as_int(val[i]));
  }
}

// ---- SpMM merged: out[:,128:256] = A h1 ; t = A h2 (fp16 gathers) -----
__global__ __launch_bounds__(256) void spmm12(
    const __half* __restrict__ h1t, const __half* __restrict__ h2t,
    const int* __restrict__ rp, const int2* __restrict__ ep,
    float* __restrict__ out, __half* __restrict__ t, int N) {
  const int r = blockIdx.x * 4 + (threadIdx.x >> 6);
  if (r >= N) return;
  const int c2 = (threadIdx.x & 63) << 1;
  const int s = rp[r], e = rp[r + 1];
  float2 p0 = make_float2(0.f, 0.f), p1 = p0, q0 = p0, q1 = p0;
  int i = s;
  for (; i + 1 < e; i += 2) {
    const int2 e0 = ep[i], e1 = ep[i + 1];
    const float v0 = __int_as_float(e0.y), v1 = __int_as_float(e1.y);
    const float2 a0 = __half22float2(*reinterpret_cast<const __half2*>(h1t + (size_t)e0.x * C + c2));
    const float2 b0 = __half22float2(*reinterpret_cast<const __half2*>(h2t + (size_t)e0.x * C + c2));
    const float2 a1 = __half22float2(*reinterpret_cast<const __half2*>(h1t + (size_t)e1.x * C + c2));
    const float2 b1 = __half22float2(*reinterpret_cast<const __half2*>(h2t + (size_t)e1.x * C + c2));
    p0.x += v0 * a0.x; p0.y += v0 * a0.y;
    q0.x += v0 * b0.x; q0.y += v0 * b0.y;
    p1.x += v1 * a1.x; p1.y += v1 * a1.y;
    q1.x += v1 * b1.x; q1.y += v1 * b1.y;
  }
  if (i < e) {
    const int2 e0 = ep[i];
    const float v0 = __int_as_float(e0.y);
    const float2 a0 = __half22float2(*reinterpret_cast<const __half2*>(h1t + (size_t)e0.x * C + c2));
    const float2 b0 = __half22float2(*reinterpret_cast<const __half2*>(h2t + (size_t)e0.x * C + c2));
    p0.x += v0 * a0.x; p0.y += v0 * a0.y;
    q0.x += v0 * b0.x; q0.y += v0 * b0.y;
  }
  float2 rp1 = make_float2(p0.x + p1.x, p0.y + p1.y);
  float2 rq = make_float2(q0.x + q1.x, q0.y + q1.y);
  *reinterpret_cast<float2*>(out + (size_t)r * 384 + C + c2) = rp1;
  *reinterpret_cast<__half2*>(t + (size_t)r * C + c2) = __float22half2_rn(rq);
}

// ---- SpMM: fp16 gather -> fp32 out column slice -----------------------
__global__ __launch_bounds__(256) void spmm_h2f(
    const __half* __restrict__ h, const int* __restrict__ rp,
    const int2* __restrict__ ep, float* __restrict__ outp, int N, int ostride) {
  const int r = blockIdx.x * 4 + (threadIdx.x >> 6);
  if (r >= N) return;
  const int c2 = (threadIdx.x & 63) << 1;
  const int s = rp[r], e = rp[r + 1];
  float2 a0 = make_float2(0.f, 0.f), a1 = a0, a2 = a0, a3 = a0;
  int i = s;
  for (; i + 3 < e; i += 4) {
    const int2 e0 = ep[i], e1 = ep[i + 1], e2 = ep[i + 2], e3 = ep[i + 3];
    const float2 g0 = __half22float2(*reinterpret_cast<const __half2*>(h + (size_t)e0.x * C + c2));
    const float2 g1 = __half22float2(*reinterpret_cast<const __half2*>(h + (size_t)e1.x * C + c2));
    const float2 g2 = __half22float2(*reinterpret_cast<const __half2*>(h + (size_t)e2.x * C + c2));
    const float2 g3 = __half22float2(*reinterpret_cast<const __half2*>(h + (size_t)e3.x * C + c2));
    const float v0 = __int_as_float(e0.y), v1 = __int_as_float(e1.y);
    const float v2 = __int_as_float(e2.y), v3 = __int_as_float(e3.y);
    a0.x += v0 * g0.x; a0.y += v0 * g0.y;
    a1.x += v1 * g1.x; a1.y += v1 * g1.y;
    a2.x += v2 * g2.x; a2.y += v2 * g2.y;
    a3.x += v3 * g3.x; a3.y += v3 * g3.y;
  }
  for (; i < e; ++i) {
    const int2 e0 = ep[i];
    const float v0 = __int_as_float(e0.y);
    const float2 g0 = __half22float2(*reinterpret_cast<const __half2*>(h + (size_t)e0.x * C + c2));
    a0.x += v0 * g0.x; a0.y += v0 * g0.y;
  }
  float2 res = make_float2((a0.x + a1.x) + (a2.x + a3.x),
                           (a0.y + a1.y) + (a2.y + a3.y));
  *reinterpret_cast<float2*>(outp + (size_t)r * ostride + c2) = res;
}

// ---- SpMM: fp16 gather -> fp16 table (fallback path) ------------------
__global__ __launch_bounds__(256) void spmm_h2h(
    const __half* __restrict__ h, const int* __restrict__ rp,
    const int2* __restrict__ ep, __half* __restrict__ outp, int N) {
  const int r = blockIdx.x * 4 + (threadIdx.x >> 6);
  if (r >= N) return;
  const int c2 = (threadIdx.x & 63) << 1;
  const int s = rp[r], e = rp[r + 1];
  float2 a0 = make_float2(0.f, 0.f), a1 = a0;
  int i = s;
  for (; i + 1 < e; i += 2) {
    const int2 e0 = ep[i], e1 = ep[i + 1];
    const float2 g0 = __half22float2(*reinterpret_cast<const __half2*>(h + (size_t)e0.x * C + c2));
    const float2 g1 = __half22float2(*reinterpret_cast<const __half2*>(h + (size_t)e1.x * C + c2));
    const float v0 = __int_as_float(e0.y), v1 = __int_as_float(e1.y);
    a0.x += v0 * g0.x; a0.y += v0 * g0.y;
    a1.x += v1 * g1.x; a1.y += v1 * g1.y;
  }
  if (i < e) {
    const int2 e0 = ep[i];
    const float v0 = __int_as_float(e0.y);
    const float2 g0 = __half22float2(*reinterpret_cast<const __half2*>(h + (size_t)e0.x * C + c2));
    a0.x += v0 * g0.x; a0.y += v0 * g0.y;
  }
  float2 res = make_float2(a0.x + a1.x, a0.y + a1.y);
  *reinterpret_cast<__half2*>(outp + (size_t)r * C + c2) = __float22half2_rn(res);
}

extern "C" void kernel_launch(void* const* d_in, const int* in_sizes, int n_in,
                              void* d_out, int out_size, void* d_ws, size_t ws_size,
                              hipStream_t stream) {
  const float* x  = (const float*)d_in[0];
  const float* W  = (const float*)d_in[1];
  const float* b  = (const float*)d_in[2];
  const float* ev = (const float*)d_in[3];
  const int*   er = (const int*)d_in[4];
  const int*   ec = (const int*)d_in[5];
  const int N = in_sizes[0] / C;
  const int E = in_sizes[3];
  float* out = (float*)d_out;

  const int NP = ((N + 63) / 64) * 64;
  char* base = (char*)d_ws;
  size_t off = 0;
  auto alloc = [&](size_t bytes) {
    char* p = base + off;
    off += (bytes + 255) & ~(size_t)255;
    return p;
  };
  __half* h1 = (__half*)alloc((size_t)N * C * 2);
  __half* h2 = (__half*)alloc((size_t)N * C * 2);
  unsigned short* xh = (unsigned short*)alloc((size_t)NP * C * 2);
  unsigned short* xl = (unsigned short*)alloc((size_t)NP * C * 2);
  unsigned short* wh = (unsigned short*)alloc(3 * 16384 * 2);
  unsigned short* wl = (unsigned short*)alloc(3 * 16384 * 2);
  int* row_ptr = (int*)alloc((size_t)(N + 1) * 4);
  int* cursor  = (int*)alloc((size_t)N * 4);
  int* bsum    = (int*)alloc(64 * 4);
  int* carry   = (int*)alloc(64 * 4);
  int2* ep     = (int2*)alloc((size_t)E * 8);
  const size_t need_t = off + (size_t)N * C * 2;
  __half* t;
  bool merged;
  if (ws_size >= need_t) { t = (__half*)alloc((size_t)N * C * 2); merged = true; }
  else                   { t = h1; merged = false; }  // h1 dead after pass-1

  const int nb = (N + 1023) / 1024;

  // prep (weights + split x)
  prep_w<<<192, 256, 0, stream>>>(W, wh, wl);
  prep_x<<<(NP * C + 255) / 256, 256, 0, stream>>>(x, xh, xl, N, NP);

  // CSR build (cursor doubles as count buffer)
  hipMemsetAsync(cursor, 0, (size_t)N * sizeof(int), stream);
  const int eb0 = (E + 255) / 256;
  const int eblocks = eb0 < 2048 ? eb0 : 2048;
  hist_rows<<<eblocks, 256, 0, stream>>>(er, cursor, E);
  scan_local<<<nb, 1024, 0, stream>>>(cursor, row_ptr, bsum, N);
  scan_carry<<<1, 64, 0, stream>>>(bsum, carry, row_ptr, nb, N);
  scan_apply<<<nb, 1024, 0, stream>>>(row_ptr, carry, cursor, N);
  scatter_edges<<<eblocks, 256, 0, stream>>>(er, ec, ev, cursor, ep, E);

  // fused linears (MFMA, LDS-staged W)
  gemm3_mfma<<<NP / 64, 256, 0, stream>>>(xh, xl, wh, wl, b, out, h1, h2, N);

  // SpMM passes
  const int sblocks = (N + 3) / 4;
  if (merged) {
    spmm12<<<sblocks, 256, 0, stream>>>(h1, h2, row_ptr, ep, out, t, N);
  } else {
    spmm_h2f<<<sblocks, 256, 0, stream>>>(h1, row_ptr, ep, out + C, N, 3 * C);
    spmm_h2h<<<sblocks, 256, 0, stream>>>(h2, row_ptr, ep, t, N);
  }
  spmm_h2f<<<sblocks, 256, 0, stream>>>(t, row_ptr, ep, out + 2 * C, N, 3 * C);
}